// Round 2
// baseline (1033.167 us; speedup 1.0000x reference)
//
#include <hip/hip_runtime.h>
#include <hip/hip_bf16.h>

#define NODES 100000
#define BN_EPS 1e-5f

// ---------------------------------------------------------------------------
// K1: Fn[n][c] = sum_ci w_n[c][ci] * x[ci][n].   x fp32 [64][N] channel-major,
// output node-major [n][c] so the edge gather reads 256B-contiguous rows.
// ---------------------------------------------------------------------------
__global__ __launch_bounds__(256) void k_gemm_n(
        const float* __restrict__ x, const float* __restrict__ wn,
        float* __restrict__ Fn) {
    __shared__ float lx[64][65];   // [ci][j]  (+1 pad: 2-way max, free)
    __shared__ float lw[64][65];   // [co][ci]
    const int t = threadIdx.x;
    const int n0 = blockIdx.x * 64;
    for (int idx = t; idx < 4096; idx += 256) {
        int r = idx >> 6, q = idx & 63;
        lw[r][q] = wn[idx];
        int n = n0 + q;
        lx[r][q] = (n < NODES) ? x[r * NODES + n] : 0.f;
    }
    __syncthreads();
    const int c = t & 63;        // lane = output channel -> coalesced stores
    const int jb = t >> 6;       // wave-uniform node sub-index
    for (int k = 0; k < 16; ++k) {
        int j = jb + 4 * k;      // wave-uniform -> lx[ci][j] broadcasts
        int n = n0 + j;
        if (n >= NODES) continue;
        float acc = 0.f;
#pragma unroll
        for (int ci = 0; ci < 64; ++ci)
            acc += lw[c][ci] * lx[ci][j];
        Fn[n * 64 + c] = acc;
    }
}

// ---------------------------------------------------------------------------
// K2: edge scatter. One wave handles 64 edges: coalesced index loads, then per
// edge a 256B contiguous gather of Fn[g][*] and 64 lane-parallel device-scope
// fp32 atomics into sums[r][*]. Lane l also counts edge l.
// ---------------------------------------------------------------------------
__global__ __launch_bounds__(256) void k_scatter(
        const float* __restrict__ Fn,
        const int* __restrict__ gidx, const int* __restrict__ ridx,
        float* __restrict__ sums, int* __restrict__ counts, int E) {
    const int wave = (int)((blockIdx.x * blockDim.x + threadIdx.x) >> 6);
    const int lane = threadIdx.x & 63;
    const int base = wave * 64;
    if (base >= E) return;
    const int nvalid = min(64, E - base);
    int g = 0, r = 0;
    if (lane < nvalid) {
        g = gidx[base + lane];
        r = ridx[base + lane];
        atomicAdd(&counts[r], 1);
    }
    for (int i = 0; i < nvalid; ++i) {
        int gg = __shfl(g, i);
        int rr = __shfl(r, i);
        float v = Fn[gg * 64 + lane];
        atomicAdd(&sums[rr * 64 + lane], v);
    }
}

// ---------------------------------------------------------------------------
// K3: recompute Fv = w_v @ x (same GEMM scheme), combine with scatter-mean,
// transpose to [c][n] into d_out, and accumulate per-channel sum/sumsq partials
// into bn[0..63]/bn[64..127].
// ---------------------------------------------------------------------------
__global__ __launch_bounds__(256) void k_combine(
        const float* __restrict__ x, const float* __restrict__ wv,
        const float* __restrict__ sums, const int* __restrict__ counts,
        float* __restrict__ outpre, float* __restrict__ bn) {
    __shared__ float lx[64][65];
    __shared__ float lw[64][65];
    __shared__ float tile[64][65];  // pre-BN values, [c][j]
    __shared__ float reds[64][4];
    __shared__ float redq[64][4];
    const int t = threadIdx.x;
    const int n0 = blockIdx.x * 64;
    for (int idx = t; idx < 4096; idx += 256) {
        int r = idx >> 6, q = idx & 63;
        lw[r][q] = wv[idx];
        int n = n0 + q;
        lx[r][q] = (n < NODES) ? x[r * NODES + n] : 0.f;
    }
    __syncthreads();
    const int c = t & 63;
    const int jb = t >> 6;
    float ls = 0.f, lq = 0.f;
    for (int k = 0; k < 16; ++k) {
        int j = jb + 4 * k;
        int n = n0 + j;
        float v = 0.f;
        if (n < NODES) {
            float fv = 0.f;
#pragma unroll
            for (int ci = 0; ci < 64; ++ci)
                fv += lw[c][ci] * lx[ci][j];
            float cnt = (float)counts[n];                  // wave-uniform
            v = sums[n * 64 + c] / fmaxf(cnt, 1.f) + fv;
            ls += v;
            lq += v * v;
        }
        tile[c][j] = v;
    }
    reds[c][jb] = ls;
    redq[c][jb] = lq;
    __syncthreads();
    const int j2 = t & 63;   // lane = node -> coalesced [c][N] stores
    const int c2 = t >> 6;
    const int n = n0 + j2;
    if (n < NODES) {
        for (int k = 0; k < 16; ++k) {
            int cc = c2 + 4 * k;
            outpre[cc * NODES + n] = tile[cc][j2];
        }
    }
    if (t < 64) {
        atomicAdd(&bn[t],      reds[t][0] + reds[t][1] + reds[t][2] + reds[t][3]);
        atomicAdd(&bn[64 + t], redq[t][0] + redq[t][1] + redq[t][2] + redq[t][3]);
    }
}

// ---------------------------------------------------------------------------
// K4: per-channel affine from batch stats + PReLU, in place on d_out [C][N].
// ---------------------------------------------------------------------------
__global__ __launch_bounds__(256) void k_final(
        float* __restrict__ out, const float* __restrict__ bn,
        const float* __restrict__ gamma, const float* __restrict__ beta,
        const float* __restrict__ pa) {
    const int c = blockIdx.y;
    const int n = blockIdx.x * 256 + threadIdx.x;
    const float invN = 1.f / (float)NODES;
    float mu = bn[c] * invN;
    float var = fmaxf(bn[64 + c] * invN - mu * mu, 0.f);
    float scale = gamma[c] * rsqrtf(var + BN_EPS);
    float shift = beta[c] - mu * scale;
    float a = pa[0];
    if (n < NODES) {
        float y = out[c * NODES + n] * scale + shift;
        y = (y >= 0.f) ? y : a * y;
        out[c * NODES + n] = y;
    }
}

extern "C" void kernel_launch(void* const* d_in, const int* in_sizes, int n_in,
                              void* d_out, int out_size, void* d_ws, size_t ws_size,
                              hipStream_t stream) {
    const float* x     = (const float*)d_in[0];   // [64][100000] fp32
    const float* w_v   = (const float*)d_in[1];   // [64][64] fp32
    const float* w_n   = (const float*)d_in[2];
    const float* gamma = (const float*)d_in[3];
    const float* beta  = (const float*)d_in[4];
    const float* pa    = (const float*)d_in[5];
    const int* ridx    = (const int*)d_in[6];
    const int* gidx    = (const int*)d_in[7];
    float* out = (float*)d_out;

    const long long N64 = (long long)NODES * 64;  // 6,400,000
    // ws layout (26.0 MB total): sums [n][c] | counts [N] | bn [128]
    float* sums   = (float*)d_ws;
    int*   counts = (int*)(sums + N64);
    float* bn     = (float*)(sums + N64 + NODES);

    // Fn is staged in d_out (dead after K2; K3 overwrites d_out with pre-BN).
    float* Fn = out;

    const int E = in_sizes[6];

    hipMemsetAsync(sums, 0, (size_t)(N64 + NODES + 128) * sizeof(float), stream);

    const int ntiles = (NODES + 63) / 64;  // 1563
    k_gemm_n<<<ntiles, 256, 0, stream>>>(x, w_n, Fn);
    k_scatter<<<(E + 255) / 256, 256, 0, stream>>>(Fn, gidx, ridx, sums, counts, E);
    k_combine<<<ntiles, 256, 0, stream>>>(x, w_v, sums, counts, out, bn);
    dim3 g4((NODES + 255) / 256, 64);
    k_final<<<g4, 256, 0, stream>>>(out, bn, gamma, beta, pa);
}

// Round 3
// 1005.843 us; speedup vs baseline: 1.0272x; 1.0272x over previous
//
#include <hip/hip_runtime.h>
#include <hip/hip_bf16.h>

#define NODES 100000
#define BN_EPS 1e-5f

// ---------------------------------------------------------------------------
// K1: Fn[n][c] = sum_ci w_n[c][ci] * x[ci][n].   x fp32 [64][N] channel-major,
// output node-major [n][c] so the edge gather reads 256B-contiguous rows.
// ---------------------------------------------------------------------------
__global__ __launch_bounds__(256) void k_gemm_n(
        const float* __restrict__ x, const float* __restrict__ wn,
        float* __restrict__ Fn) {
    __shared__ float lx[64][65];   // [ci][j]  (+1 pad: 2-way max, free)
    __shared__ float lw[64][65];   // [co][ci]
    const int t = threadIdx.x;
    const int n0 = blockIdx.x * 64;
    for (int idx = t; idx < 4096; idx += 256) {
        int r = idx >> 6, q = idx & 63;
        lw[r][q] = wn[idx];
        int n = n0 + q;
        lx[r][q] = (n < NODES) ? x[r * NODES + n] : 0.f;
    }
    __syncthreads();
    const int c = t & 63;        // lane = output channel -> coalesced stores
    const int jb = t >> 6;       // wave-uniform node sub-index
    for (int k = 0; k < 16; ++k) {
        int j = jb + 4 * k;      // wave-uniform -> lx[ci][j] broadcasts
        int n = n0 + j;
        if (n >= NODES) continue;
        float acc = 0.f;
#pragma unroll
        for (int ci = 0; ci < 64; ++ci)
            acc += lw[c][ci] * lx[ci][j];
        Fn[n * 64 + c] = acc;
    }
}

// ---------------------------------------------------------------------------
// CSR build: histogram -> scan -> reorder (counting sort by destination).
// ---------------------------------------------------------------------------
__global__ __launch_bounds__(256) void k_hist(
        const int* __restrict__ ridx, int* __restrict__ counts, int E) {
    int e = blockIdx.x * 256 + threadIdx.x;
    if (e < E) atomicAdd(&counts[ridx[e]], 1);
}

__global__ __launch_bounds__(1024) void k_scan(
        const int* __restrict__ counts, int* __restrict__ start,
        int* __restrict__ cursor) {
    __shared__ int part[1024];
    const int t = threadIdx.x;
    const int CH = (NODES + 1023) / 1024;  // 98
    const int base = t * CH;
    int s = 0;
    for (int i = 0; i < CH; ++i) {
        int j = base + i;
        if (j < NODES) s += counts[j];
    }
    part[t] = s;
    __syncthreads();
    for (int off = 1; off < 1024; off <<= 1) {   // Hillis-Steele inclusive
        int v = part[t];
        int add = (t >= off) ? part[t - off] : 0;
        __syncthreads();
        part[t] = v + add;
        __syncthreads();
    }
    int run = (t == 0) ? 0 : part[t - 1];  // exclusive prefix of this chunk
    for (int i = 0; i < CH; ++i) {
        int j = base + i;
        if (j < NODES) {
            start[j] = run;
            cursor[j] = run;
            run += counts[j];
        }
    }
    if (t == 1023) start[NODES] = run;     // == E
}

__global__ __launch_bounds__(256) void k_reorder(
        const int* __restrict__ ridx, const int* __restrict__ gidx,
        int* __restrict__ cursor, int* __restrict__ sortedG, int E) {
    int e = blockIdx.x * 256 + threadIdx.x;
    if (e < E) {
        int r = ridx[e];
        int pos = atomicAdd(&cursor[r], 1);
        sortedG[pos] = gidx[e];
    }
}

// ---------------------------------------------------------------------------
// Segment mean (pull): one wave per node, lane = channel. Per edge one
// wave-uniform index load + one contiguous 256B gather of Fn. No atomics.
// ---------------------------------------------------------------------------
__global__ __launch_bounds__(256) void k_segreduce(
        const float* __restrict__ Fn, const int* __restrict__ sortedG,
        const int* __restrict__ start, float* __restrict__ mean) {
    const int n = (int)((blockIdx.x * (unsigned)blockDim.x + threadIdx.x) >> 6);
    const int lane = threadIdx.x & 63;
    if (n >= NODES) return;
    const int s0 = start[n], s1 = start[n + 1];
    float a0 = 0.f, a1 = 0.f, a2 = 0.f, a3 = 0.f;
    int i = s0;
    for (; i + 3 < s1; i += 4) {           // 4 gathers in flight
        int g0 = sortedG[i],     g1 = sortedG[i + 1];
        int g2 = sortedG[i + 2], g3 = sortedG[i + 3];
        a0 += Fn[g0 * 64 + lane];
        a1 += Fn[g1 * 64 + lane];
        a2 += Fn[g2 * 64 + lane];
        a3 += Fn[g3 * 64 + lane];
    }
    for (; i < s1; ++i) a0 += Fn[sortedG[i] * 64 + lane];
    float cnt = (float)(s1 - s0);
    mean[n * 64 + lane] = ((a0 + a1) + (a2 + a3)) / fmaxf(cnt, 1.f);
}

// ---------------------------------------------------------------------------
// K3: recompute Fv = w_v @ x, add mean (or sums/cnt in fallback mode),
// transpose to [c][n] into d_out, accumulate per-channel sum/sumsq into bn.
// ---------------------------------------------------------------------------
__global__ __launch_bounds__(256) void k_combine(
        const float* __restrict__ x, const float* __restrict__ wv,
        const float* __restrict__ sums, const int* __restrict__ counts,
        const int divide,
        float* __restrict__ outpre, float* __restrict__ bn) {
    __shared__ float lx[64][65];
    __shared__ float lw[64][65];
    __shared__ float tile[64][65];  // pre-BN values, [c][j]
    __shared__ float reds[64][4];
    __shared__ float redq[64][4];
    const int t = threadIdx.x;
    const int n0 = blockIdx.x * 64;
    for (int idx = t; idx < 4096; idx += 256) {
        int r = idx >> 6, q = idx & 63;
        lw[r][q] = wv[idx];
        int n = n0 + q;
        lx[r][q] = (n < NODES) ? x[r * NODES + n] : 0.f;
    }
    __syncthreads();
    const int c = t & 63;
    const int jb = t >> 6;
    float ls = 0.f, lq = 0.f;
    for (int k = 0; k < 16; ++k) {
        int j = jb + 4 * k;
        int n = n0 + j;
        float v = 0.f;
        if (n < NODES) {
            float fv = 0.f;
#pragma unroll
            for (int ci = 0; ci < 64; ++ci)
                fv += lw[c][ci] * lx[ci][j];
            v = sums[n * 64 + c];
            if (divide) v /= fmaxf((float)counts[n], 1.f);
            v += fv;
            ls += v;
            lq += v * v;
        }
        tile[c][j] = v;
    }
    reds[c][jb] = ls;
    redq[c][jb] = lq;
    __syncthreads();
    const int j2 = t & 63;   // lane = node -> coalesced [c][N] stores
    const int c2 = t >> 6;
    const int n = n0 + j2;
    if (n < NODES) {
        for (int k = 0; k < 16; ++k) {
            int cc = c2 + 4 * k;
            outpre[cc * NODES + n] = tile[cc][j2];
        }
    }
    if (t < 64) {
        atomicAdd(&bn[t],      reds[t][0] + reds[t][1] + reds[t][2] + reds[t][3]);
        atomicAdd(&bn[64 + t], redq[t][0] + redq[t][1] + redq[t][2] + redq[t][3]);
    }
}

// ---------------------------------------------------------------------------
// K4: per-channel affine from batch stats + PReLU, in place on d_out [C][N].
// ---------------------------------------------------------------------------
__global__ __launch_bounds__(256) void k_final(
        float* __restrict__ out, const float* __restrict__ bn,
        const float* __restrict__ gamma, const float* __restrict__ beta,
        const float* __restrict__ pa) {
    const int c = blockIdx.y;
    const int n = blockIdx.x * 256 + threadIdx.x;
    const float invN = 1.f / (float)NODES;
    float mu = bn[c] * invN;
    float var = fmaxf(bn[64 + c] * invN - mu * mu, 0.f);
    float scale = gamma[c] * rsqrtf(var + BN_EPS);
    float shift = beta[c] - mu * scale;
    float a = pa[0];
    if (n < NODES) {
        float y = out[c * NODES + n] * scale + shift;
        y = (y >= 0.f) ? y : a * y;
        out[c * NODES + n] = y;
    }
}

// ---------------------------------------------------------------------------
// Fallback (ws too small for CSR): round-2 atomic scatter, proven correct.
// ---------------------------------------------------------------------------
__global__ __launch_bounds__(256) void k_scatter(
        const float* __restrict__ Fn,
        const int* __restrict__ gidx, const int* __restrict__ ridx,
        float* __restrict__ sums, int* __restrict__ counts, int E) {
    const int wave = (int)((blockIdx.x * blockDim.x + threadIdx.x) >> 6);
    const int lane = threadIdx.x & 63;
    const int base = wave * 64;
    if (base >= E) return;
    const int nvalid = min(64, E - base);
    int g = 0, r = 0;
    if (lane < nvalid) {
        g = gidx[base + lane];
        r = ridx[base + lane];
        atomicAdd(&counts[r], 1);
    }
    for (int i = 0; i < nvalid; ++i) {
        int gg = __shfl(g, i);
        int rr = __shfl(r, i);
        float v = Fn[gg * 64 + lane];
        atomicAdd(&sums[rr * 64 + lane], v);
    }
}

extern "C" void kernel_launch(void* const* d_in, const int* in_sizes, int n_in,
                              void* d_out, int out_size, void* d_ws, size_t ws_size,
                              hipStream_t stream) {
    const float* x     = (const float*)d_in[0];   // [64][100000] fp32
    const float* w_v   = (const float*)d_in[1];   // [64][64] fp32
    const float* w_n   = (const float*)d_in[2];
    const float* gamma = (const float*)d_in[3];
    const float* beta  = (const float*)d_in[4];
    const float* pa    = (const float*)d_in[5];
    const int* ridx    = (const int*)d_in[6];
    const int* gidx    = (const int*)d_in[7];
    float* out = (float*)d_out;

    const int E = in_sizes[6];
    const long long N64 = (long long)NODES * 64;  // 6,400,000
    const int ntiles = (NODES + 63) / 64;         // 1563
    const dim3 g4((NODES + 255) / 256, 64);

    // CSR-path ws layout: mean[N64] f32 | counts[N] i32 | bn[128] f32 |
    //                     start[N+1] i32 | cursor[N] i32 | sortedG[E] i32
    size_t need = ((size_t)N64 + NODES + 128 + (NODES + 1) + NODES + (size_t)E)
                  * sizeof(float);

    if (ws_size >= need) {
        float* mean   = (float*)d_ws;
        int*   counts = (int*)(mean + N64);
        float* bn     = (float*)(counts + NODES);
        int*   start  = (int*)(bn + 128);
        int*   cursor = start + NODES + 1;
        int*   sortedG = cursor + NODES;
        float* Fn = out;  // staged in d_out; dead after segreduce

        // zero counts + bn in one memset (contiguous)
        hipMemsetAsync(counts, 0, (size_t)(NODES + 128) * sizeof(int), stream);

        k_hist<<<(E + 255) / 256, 256, 0, stream>>>(ridx, counts, E);
        k_scan<<<1, 1024, 0, stream>>>(counts, start, cursor);
        k_reorder<<<(E + 255) / 256, 256, 0, stream>>>(ridx, gidx, cursor,
                                                       sortedG, E);
        k_gemm_n<<<ntiles, 256, 0, stream>>>(x, w_n, Fn);
        k_segreduce<<<(NODES * 64 + 255) / 256, 256, 0, stream>>>(Fn, sortedG,
                                                                  start, mean);
        k_combine<<<ntiles, 256, 0, stream>>>(x, w_v, mean, counts, 0, out, bn);
        k_final<<<g4, 256, 0, stream>>>(out, bn, gamma, beta, pa);
    } else {
        // Fallback: round-2 atomic-scatter path (26.0 MB ws).
        float* sums   = (float*)d_ws;
        int*   counts = (int*)(sums + N64);
        float* bn     = (float*)(sums + N64 + NODES);
        float* Fn = out;

        hipMemsetAsync(sums, 0, (size_t)(N64 + NODES + 128) * sizeof(float),
                       stream);
        k_gemm_n<<<ntiles, 256, 0, stream>>>(x, w_n, Fn);
        k_scatter<<<(E + 255) / 256, 256, 0, stream>>>(Fn, gidx, ridx, sums,
                                                       counts, E);
        k_combine<<<ntiles, 256, 0, stream>>>(x, w_v, sums, counts, 1, out, bn);
        k_final<<<g4, 256, 0, stream>>>(out, bn, gamma, beta, pa);
    }
}